// Round 1
// baseline (103.691 us; speedup 1.0000x reference)
//
#include <hip/hip_runtime.h>
#include <hip/hip_bf16.h>
#include <math.h>

#define DIN 512
#define DF 256
#define LSEQ 1024
#define NTOT 8192

typedef __attribute__((ext_vector_type(8))) short short8;
typedef __attribute__((ext_vector_type(4))) short short4v;
typedef __attribute__((ext_vector_type(4))) float f32x4;

__device__ __forceinline__ short f2bf(float x) {
  union { float f; unsigned u; } un; un.f = x;
  unsigned r = un.u + 0x7fffu + ((un.u >> 16) & 1u);  // RNE (inputs finite)
  return (short)(r >> 16);
}
__device__ __forceinline__ float bf2f(short s) {
  union { unsigned u; float f; } un; un.u = ((unsigned)(unsigned short)s) << 16;
  return un.f;
}

// ---------- kernel 1: W [DIN][DF] f32 -> Wt [DF][DIN] bf16 ----------
__global__ __launch_bounds__(256) void prep_w_kernel(const float* __restrict__ W,
                                                     short* __restrict__ Wt) {
  int idx = blockIdx.x * 256 + threadIdx.x;   // over DF*DIN = 131072
  int c = idx >> 9;            // / DIN
  int k = idx & (DIN - 1);
  Wt[idx] = f2bf(W[(size_t)k * DF + c]);
}

// ---------- kernel 2: projection emb = relu(feat @ W + b), bf16 out ----------
// BM=64 rows/block, full N=256 cols, BK=32. 4 waves in 2x2 (each 32 rows x 128 cols).
#define PBM 64
#define PBK 32
#define PPAD 40   // padded LDS row (bf16 elems): 80B stride -> 2-way (free) b128 conflicts

__global__ __launch_bounds__(256) void proj_kernel(const float* __restrict__ f1,
                                                   const float* __restrict__ f2,
                                                   const short* __restrict__ Wt,
                                                   const float* __restrict__ bias,
                                                   short* __restrict__ emb1,
                                                   short* __restrict__ emb2) {
  const float* feat = blockIdx.y ? f2 : f1;
  short* emb = blockIdx.y ? emb2 : emb1;
  __shared__ short ldsA[PBM * PPAD];
  __shared__ short ldsB[DF * PPAD];
  const int tid = threadIdx.x;
  const int lane = tid & 63, wv = tid >> 6;
  const int wrow = (wv & 1) * 32, wcol = (wv >> 1) * 128;
  const int l15 = lane & 15, lk = (lane >> 4) * 8;
  const int rowbase = blockIdx.x * PBM;

  f32x4 acc[2][8];
#pragma unroll
  for (int mi = 0; mi < 2; ++mi)
#pragma unroll
    for (int nf = 0; nf < 8; ++nf) acc[mi][nf] = f32x4{0.f, 0.f, 0.f, 0.f};

  for (int kb = 0; kb < DIN; kb += PBK) {
    __syncthreads();   // previous iteration's frag reads complete before overwrite
    // stage A: 64x32 f32 -> bf16 (512 float4 chunks, 2/thread)
#pragma unroll
    for (int i = 0; i < 2; ++i) {
      int flat = tid * 2 + i;
      int r = flat >> 3, kq = (flat & 7) * 4;
      f32x4 v = *(const f32x4*)(feat + (size_t)(rowbase + r) * DIN + kb + kq);
      short4v h;
      h[0] = f2bf(v[0]); h[1] = f2bf(v[1]); h[2] = f2bf(v[2]); h[3] = f2bf(v[3]);
      *(short4v*)(ldsA + r * PPAD + kq) = h;
    }
    // stage B: 256x32 bf16 from Wt (1024 short8 chunks, 4/thread)
#pragma unroll
    for (int i = 0; i < 4; ++i) {
      int flat = tid * 4 + i;
      int c = flat >> 2, kq = (flat & 3) * 8;
      short8 v = *(const short8*)(Wt + (size_t)c * DIN + kb + kq);
      *(short8*)(ldsB + c * PPAD + kq) = v;
    }
    __syncthreads();
    short8 af[2], bf[8];
#pragma unroll
    for (int mi = 0; mi < 2; ++mi)
      af[mi] = *(const short8*)(ldsA + (wrow + mi * 16 + l15) * PPAD + lk);
#pragma unroll
    for (int nf = 0; nf < 8; ++nf)
      bf[nf] = *(const short8*)(ldsB + (wcol + nf * 16 + l15) * PPAD + lk);
#pragma unroll
    for (int mi = 0; mi < 2; ++mi)
#pragma unroll
      for (int nf = 0; nf < 8; ++nf)
        acc[mi][nf] = __builtin_amdgcn_mfma_f32_16x16x32_bf16(af[mi], bf[nf], acc[mi][nf], 0, 0, 0);
  }
  // epilogue: bias + relu + bf16 store. C layout: col=lane&15, row=(lane>>4)*4+reg
  const int r4 = (lane >> 4) * 4;
#pragma unroll
  for (int mi = 0; mi < 2; ++mi) {
    int row0 = rowbase + wrow + mi * 16 + r4;
#pragma unroll
    for (int nf = 0; nf < 8; ++nf) {
      int col = wcol + nf * 16 + l15;
      float bb = bias[col];
#pragma unroll
      for (int r = 0; r < 4; ++r) {
        float v = acc[mi][nf][r] + bb;
        v = v > 0.f ? v : 0.f;
        emb[(size_t)(row0 + r) * DF + col] = f2bf(v);
      }
    }
  }
}

// ---------- kernel 3: positive = dot(e1,e2) + banded diag means ----------
__global__ __launch_bounds__(64) void positive_kernel(const short* __restrict__ emb1,
                                                      const short* __restrict__ emb2,
                                                      const int* __restrict__ prs,
                                                      const int* __restrict__ prt,
                                                      float* __restrict__ pos) {
  const int row = blockIdx.x;
  const int b = row >> 10, j = row & (LSEQ - 1);
  const int lane = threadIdx.x;
  const int rs = prs[0], rt = prt[0];
  float a1[4], a2[4];
  {
    short4v v1 = *(const short4v*)(emb1 + (size_t)row * DF + lane * 4);
    short4v v2 = *(const short4v*)(emb2 + (size_t)row * DF + lane * 4);
#pragma unroll
    for (int i = 0; i < 4; ++i) { a1[i] = bf2f(v1[i]); a2[i] = bf2f(v2[i]); }
  }
  float dot12 = 0.f, p11 = 0.f, p22 = 0.f, p12 = 0.f;
#pragma unroll
  for (int i = 0; i < 4; ++i) dot12 += a1[i] * a2[i];
  int rmax = rs > rt ? rs : rt;
  for (int d = -rmax; d <= rmax; ++d) {
    int k = j + d;
    if (k < 0 || k >= LSEQ) continue;
    size_t koff = (size_t)(b * LSEQ + k) * DF + lane * 4;
    short4v w1 = *(const short4v*)(emb1 + koff);
    short4v w2 = *(const short4v*)(emb2 + koff);
    float d11 = 0.f, d22 = 0.f, d12 = 0.f;
#pragma unroll
    for (int i = 0; i < 4; ++i) {
      float e1k = bf2f(w1[i]), e2k = bf2f(w2[i]);
      d11 += a1[i] * e1k;
      d22 += a2[i] * e2k;
      d12 += a1[i] * e2k;
    }
    if (d >= -rs && d <= rs) { p11 += d11; p22 += d22; }
    if (d >= -rt && d <= rt) { p12 += d12; }
  }
#pragma unroll
  for (int m = 1; m < 64; m <<= 1) {
    dot12 += __shfl_xor(dot12, m);
    p11 += __shfl_xor(p11, m);
    p22 += __shfl_xor(p22, m);
    p12 += __shfl_xor(p12, m);
  }
  if (lane == 0) {
    float res = dot12;
    if (rs > 0) {
      int lo = j - rs < 0 ? 0 : j - rs;
      int hi = j + rs > LSEQ - 1 ? LSEQ - 1 : j + rs;
      res += (p11 + p22) / (float)(hi - lo + 1);
    }
    if (rt > 0) {
      int lo = j - rt < 0 ? 0 : j - rt;
      int hi = j + rt > LSEQ - 1 ? LSEQ - 1 : j + rt;
      res += p12 / (float)(hi - lo + 1);
    }
    pos[row] = res;
  }
}

// ---------- kernel 4: flash-style row logsumexp of e1 @ e2^T ----------
// 128 rows/block (4 waves x 32 rows), A (e1, K=256) held in registers.
// e2 column tiles of 64 streamed through LDS, XOR-swizzled (slot = kblk ^ (col&7))
// so ds_read_b128 frag reads are 2-way (free) instead of 16-way conflicted.
// Columns split into 8 chunks across blockIdx.y; per-(row,chunk) (m,s) to ws.
#define NBM 128
#define NBN 64
#define NCHUNK 8
#define CHW (NTOT / NCHUNK)   // 1024
#define NT (CHW / NBN)        // 16

__global__ __launch_bounds__(256) void negative_kernel(const short* __restrict__ e1,
                                                       const short* __restrict__ e2,
                                                       float* __restrict__ mpart,
                                                       float* __restrict__ spart) {
  __shared__ short ldsB[NBN * DF];   // 32KB
  const int tid = threadIdx.x;
  const int lane = tid & 63, wv = tid >> 6;
  const int l15 = lane & 15, lk16 = lane >> 4;
  const int rb = blockIdx.x, chunk = blockIdx.y;
  const int rowbase = rb * NBM + wv * 32;
  const int colbase0 = chunk * CHW;

  // A fragments for this wave's 32 rows, full K=256: 2 m-frags x 8 k-steps
  short8 a[2][8];
#pragma unroll
  for (int mi = 0; mi < 2; ++mi)
#pragma unroll
    for (int ks = 0; ks < 8; ++ks)
      a[mi][ks] = *(const short8*)(e1 + (size_t)(rowbase + mi * 16 + l15) * DF + ks * 32 + lk16 * 8);

  float mrun[8], srun[8];
#pragma unroll
  for (int i = 0; i < 8; ++i) { mrun[i] = -1e30f; srun[i] = 0.f; }

  short8 st[8];
  {
    const short* src = e2 + (size_t)colbase0 * DF;
#pragma unroll
    for (int it = 0; it < 8; ++it) {
      int S = it * 256 + tid;
      int c = S >> 5, kblk = S & 31;
      st[it] = *(const short8*)(src + (size_t)c * DF + kblk * 8);
    }
  }
  for (int t = 0; t < NT; ++t) {
    __syncthreads();
#pragma unroll
    for (int it = 0; it < 8; ++it) {
      int S = it * 256 + tid;
      int c = S >> 5, kblk = S & 31;
      int slot = kblk ^ (c & 7);
      *(short8*)(ldsB + (c * 32 + slot) * 8) = st[it];
    }
    __syncthreads();
    if (t + 1 < NT) {   // prefetch next tile; vmcnt drains at next iter's ds_write
      const short* src = e2 + (size_t)(colbase0 + (t + 1) * NBN) * DF;
#pragma unroll
      for (int it = 0; it < 8; ++it) {
        int S = it * 256 + tid;
        int c = S >> 5, kblk = S & 31;
        st[it] = *(const short8*)(src + (size_t)c * DF + kblk * 8);
      }
    }
    f32x4 acc[2][4];
#pragma unroll
    for (int mi = 0; mi < 2; ++mi)
#pragma unroll
      for (int nf = 0; nf < 4; ++nf) acc[mi][nf] = f32x4{0.f, 0.f, 0.f, 0.f};
#pragma unroll
    for (int ks = 0; ks < 8; ++ks) {
      short8 bfr[4];
#pragma unroll
      for (int nf = 0; nf < 4; ++nf) {
        int c = nf * 16 + l15;
        int kblk = ks * 4 + lk16;
        int slot = kblk ^ (c & 7);
        bfr[nf] = *(const short8*)(ldsB + (c * 32 + slot) * 8);
      }
#pragma unroll
      for (int mi = 0; mi < 2; ++mi)
#pragma unroll
        for (int nf = 0; nf < 4; ++nf)
          acc[mi][nf] = __builtin_amdgcn_mfma_f32_16x16x32_bf16(a[mi][ks], bfr[nf], acc[mi][nf], 0, 0, 0);
    }
    // per-lane online max/sum over this lane's own 4 columns per row-slot
#pragma unroll
    for (int mi = 0; mi < 2; ++mi)
#pragma unroll
      for (int r = 0; r < 4; ++r) {
        int s8 = mi * 4 + r;
        float v0 = acc[mi][0][r], v1 = acc[mi][1][r], v2 = acc[mi][2][r], v3 = acc[mi][3][r];
        float mx = fmaxf(fmaxf(v0, v1), fmaxf(v2, v3));
        float mn = fmaxf(mrun[s8], mx);
        float sc = __expf(mrun[s8] - mn);
        float sm = __expf(v0 - mn) + __expf(v1 - mn) + __expf(v2 - mn) + __expf(v3 - mn);
        srun[s8] = srun[s8] * sc + sm;
        mrun[s8] = mn;
      }
  }
  // merge (m,s) across the 16 lanes (same row) of each lane-group, then write
#pragma unroll
  for (int mi = 0; mi < 2; ++mi)
#pragma unroll
    for (int r = 0; r < 4; ++r) {
      int s8 = mi * 4 + r;
      float m = mrun[s8], s = srun[s8];
#pragma unroll
      for (int msk = 1; msk < 16; msk <<= 1) {
        float mo = __shfl_xor(m, msk);
        float so = __shfl_xor(s, msk);
        float mn = fmaxf(m, mo);
        s = s * __expf(m - mn) + so * __expf(mo - mn);
        m = mn;
      }
      if (l15 == 0) {
        int row = rowbase + mi * 16 + lk16 * 4 + r;
        mpart[chunk * NTOT + row] = m;
        spart[chunk * NTOT + row] = s;
      }
    }
}

// ---------- kernel 5: combine chunks, loss = mean(lse - pos) - log N ----------
__global__ __launch_bounds__(256) void finalize_kernel(const float* __restrict__ pos,
                                                       const float* __restrict__ mpart,
                                                       const float* __restrict__ spart,
                                                       float* __restrict__ out) {
  __shared__ float red[256];
  int tid = threadIdx.x;
  float acc = 0.f;
  for (int row = tid; row < NTOT; row += 256) {
    float m = -1e30f;
#pragma unroll
    for (int c = 0; c < NCHUNK; ++c) m = fmaxf(m, mpart[c * NTOT + row]);
    float s = 0.f;
#pragma unroll
    for (int c = 0; c < NCHUNK; ++c) s += spart[c * NTOT + row] * __expf(mpart[c * NTOT + row] - m);
    float lse = m + logf(s);
    acc += (lse - pos[row]);
  }
  red[tid] = acc;
  __syncthreads();
  for (int s = 128; s > 0; s >>= 1) {
    if (tid < s) red[tid] += red[tid + s];
    __syncthreads();
  }
  if (tid == 0) out[0] = red[0] / (float)NTOT - logf((float)NTOT);
}

extern "C" void kernel_launch(void* const* d_in, const int* in_sizes, int n_in,
                              void* d_out, int out_size, void* d_ws, size_t ws_size,
                              hipStream_t stream) {
  const float* f1 = (const float*)d_in[0];
  const float* f2 = (const float*)d_in[1];
  const float* W = (const float*)d_in[2];
  const float* bias = (const float*)d_in[3];
  const int* prs = (const int*)d_in[4];
  const int* prt = (const int*)d_in[5];
  float* out = (float*)d_out;

  char* ws = (char*)d_ws;
  short* Wt = (short*)(ws);                                      // 256 KB
  short* emb1 = (short*)(ws + (256 << 10));                      // 4 MB
  short* emb2 = (short*)(ws + (256 << 10) + (4 << 20));          // 4 MB
  float* pos = (float*)(ws + (256 << 10) + (8 << 20));           // 32 KB
  float* mpart = (float*)(ws + (256 << 10) + (8 << 20) + (32 << 10));          // 256 KB
  float* spart = (float*)(ws + (256 << 10) + (8 << 20) + (32 << 10) + (256 << 10)); // 256 KB

  prep_w_kernel<<<(DF * DIN) / 256, 256, 0, stream>>>(W, Wt);
  proj_kernel<<<dim3(NTOT / PBM, 2), 256, 0, stream>>>(f1, f2, Wt, bias, emb1, emb2);
  positive_kernel<<<NTOT, 64, 0, stream>>>(emb1, emb2, prs, prt, pos);
  negative_kernel<<<dim3(NTOT / NBM, NCHUNK), 256, 0, stream>>>(emb1, emb2, mpart, spart);
  finalize_kernel<<<1, 256, 0, stream>>>(pos, mpart, spart, out);
}